// Round 1
// baseline (694.393 us; speedup 1.0000x reference)
//
#include <hip/hip_runtime.h>
#include <hip/hip_bf16.h>

typedef __bf16        bf16x8 __attribute__((ext_vector_type(8)));
typedef float         f32x4  __attribute__((ext_vector_type(4)));
typedef unsigned int  u32x4  __attribute__((ext_vector_type(4)));
typedef unsigned int   u32;
typedef unsigned short u16;

// round-to-nearest-even f32 -> bf16 (inputs are finite normals)
__device__ __forceinline__ u16 f32_to_bf16(float f) {
    u32 u = __builtin_bit_cast(u32, f);
    u = (u + 0x7FFFu + ((u >> 16) & 1u)) >> 16;
    return (u16)u;
}
__device__ __forceinline__ u32 pack2bf(float a, float b) {
    return (u32)f32_to_bf16(a) | ((u32)f32_to_bf16(b) << 16);
}

// ---------------- kernel 1: build conv weights, bf16, layout [kh*5+kw][oc2][ic2]
__global__ void build_c(const float* __restrict__ wxx,
                        const float* __restrict__ wid,
                        const float* __restrict__ XX,
                        const float* __restrict__ ident,
                        const int*   __restrict__ indsxx,
                        const int*   __restrict__ indsid,
                        u16*         __restrict__ cb)
{
    int idx = blockIdx.x * 256 + threadIdx.x;          // 25*128*128 = 409600
    if (idx >= 25 * 128 * 128) return;
    int b = idx & 127;            // ic2
    int a = (idx >> 7) & 127;     // oc2
    int t = idx >> 14;            // kh*5+kw
    int w2 = (a >> 1) * 64 + (b >> 1);
    float v = wxx[w2 * 5 + indsxx[t]] * XX[(a * 128 + b) * 25 + t]
            + ident[a * 128 + b]      * wid[w2 * 6 + indsid[t]];
    cb[idx] = f32_to_bf16(v);
}

// ---------------- kernel 2: implicit-GEMM conv via bf16 MFMA
// block: 256 thr = 4 waves (2m x 2n). tile: 128 oc x (2 rows x 128 w).
__global__ void __launch_bounds__(256, 2)
conv_mfma(const float* __restrict__ x,
          const u16*   __restrict__ cb,
          float*       __restrict__ out)
{
    __shared__ u32x4 lds4[2 * 132 * 8];                 // 2 row-slots, [w' 0..131][64 ic bf16]
    u32* lds32 = reinterpret_cast<u32*>(lds4);

    const int tid    = threadIdx.x;
    const int lane   = tid & 63;
    const int wv     = tid >> 6;
    const int wave_m = wv >> 1;                          // oc half (0/1)
    const int wave_n = wv & 1;                           // row within pair
    const int l15    = lane & 15;
    const int hi     = lane >> 4;                        // k-chunk within frag

    // bijective XCD swizzle: nwg=1024, 128 consecutive tiles per XCD
    const int bid = blockIdx.x;
    const int swz = (bid & 7) * 128 + (bid >> 3);
    const int bb  = swz >> 6;                            // batch
    const int h0  = (swz & 63) << 1;                     // output row pair base

    // zero halo columns w' in {0,1,130,131} once (never overwritten)
    if (tid < 64) {
        const int wtab[4] = {0, 1, 130, 131};
        int slot = tid >> 5;
        int wp   = wtab[(tid >> 3) & 3];
        u32x4 z = {0, 0, 0, 0};
        lds4[((slot * 132 + wp) << 3) + (tid & 7)] = z;
    }

    f32x4 acc[4][8];
    #pragma unroll
    for (int i = 0; i < 4; ++i)
        #pragma unroll
        for (int j = 0; j < 8; ++j) {
            f32x4 z = {0.f, 0.f, 0.f, 0.f};
            acc[i][j] = z;
        }

    const int q   = tid & 31;                            // w-quad (w = 4q)
    const int icp = (tid >> 5) << 1;                     // ic' pair base

    for (int kh = 0; kh < 5; ++kh) {
        const int hp0 = h0 + kh - 2;                     // x row for slot 0
        for (int ich = 0; ich < 2; ++ich) {
            __syncthreads();                             // prev reads done
            // stage: 2 slots x 64 ic x 128 w, transposed to [w'][ic], bf16
            #pragma unroll
            for (int it = 0; it < 8; ++it) {
                const int slot = it >> 2;
                const int icl  = icp + ((it & 3) << 4);  // 0..63 (pair base)
                const int hp   = hp0 + slot;
                f32x4 v0 = {0.f, 0.f, 0.f, 0.f};
                f32x4 v1 = {0.f, 0.f, 0.f, 0.f};
                if (0 <= hp && hp < 128) {
                    const float* base = x + (((bb * 128 + (ich << 6) + icl) * 128 + hp) * 128 + (q << 2));
                    v0 = *reinterpret_cast<const f32x4*>(base);
                    v1 = *reinterpret_cast<const f32x4*>(base + 128 * 128);
                }
                #pragma unroll
                for (int j = 0; j < 4; ++j) {
                    const int wp    = (q << 2) + 2 + j;
                    const int chunk = ((slot * 132 + wp) << 3)
                                    + ((icl >> 3) ^ ((wp ^ (wp >> 2)) & 7));
                    lds32[(chunk << 2) + ((icl & 7) >> 1)] = pack2bf(v0[j], v1[j]);
                }
            }
            __syncthreads();

            #pragma unroll
            for (int kw = 0; kw < 5; ++kw) {
                // A base: cb[(kh*5+kw)][wave_m*64 + l15][ich*64 + hi*8]
                const u16* cb0 = cb + (((kh * 5 + kw) * 128 + wave_m * 64 + l15) << 7)
                               + (ich << 6) + (hi << 3);
                #pragma unroll
                for (int kk = 0; kk < 2; ++kk) {
                    const bf16x8 a0 = *reinterpret_cast<const bf16x8*>(cb0 + kk * 32);
                    const bf16x8 a1 = *reinterpret_cast<const bf16x8*>(cb0 + kk * 32 + 2048);
                    const bf16x8 a2 = *reinterpret_cast<const bf16x8*>(cb0 + kk * 32 + 4096);
                    const bf16x8 a3 = *reinterpret_cast<const bf16x8*>(cb0 + kk * 32 + 6144);
                    #pragma unroll
                    for (int nf = 0; nf < 8; ++nf) {
                        const int wp    = nf * 16 + l15 + kw;       // 0..131
                        const int chunk = ((wave_n * 132 + wp) << 3)
                                        + (((kk << 2) + hi) ^ ((wp ^ (wp >> 2)) & 7));
                        const bf16x8 bfrag = __builtin_bit_cast(bf16x8, lds4[chunk]);
                        acc[0][nf] = __builtin_amdgcn_mfma_f32_16x16x32_bf16(a0, bfrag, acc[0][nf], 0, 0, 0);
                        acc[1][nf] = __builtin_amdgcn_mfma_f32_16x16x32_bf16(a1, bfrag, acc[1][nf], 0, 0, 0);
                        acc[2][nf] = __builtin_amdgcn_mfma_f32_16x16x32_bf16(a2, bfrag, acc[2][nf], 0, 0, 0);
                        acc[3][nf] = __builtin_amdgcn_mfma_f32_16x16x32_bf16(a3, bfrag, acc[3][nf], 0, 0, 0);
                    }
                }
            }
        }
    }

    // epilogue: D frag mapping col=lane&15 (w), row=(lane>>4)*4+reg (oc)
    const int h = h0 + wave_n;
    #pragma unroll
    for (int mf = 0; mf < 4; ++mf) {
        #pragma unroll
        for (int r = 0; r < 4; ++r) {
            float* orow = out + (((bb * 128 + wave_m * 64 + mf * 16 + (hi << 2) + r) * 128 + h) * 128) + l15;
            #pragma unroll
            for (int nf = 0; nf < 8; ++nf)
                orow[nf * 16] = acc[mf][nf][r];
        }
    }
}

extern "C" void kernel_launch(void* const* d_in, const int* in_sizes, int n_in,
                              void* d_out, int out_size, void* d_ws, size_t ws_size,
                              hipStream_t stream)
{
    const float* x    = (const float*)d_in[0];
    const float* wxx  = (const float*)d_in[1];
    const float* wi   = (const float*)d_in[2];
    const float* XX   = (const float*)d_in[3];
    const float* iden = (const float*)d_in[4];
    const int*   ixx  = (const int*)d_in[5];
    const int*   iid  = (const int*)d_in[6];

    u16* cbuf = (u16*)d_ws;                              // 819200 B of scratch

    build_c<<<1600, 256, 0, stream>>>(wxx, wi, XX, iden, ixx, iid, cbuf);
    conv_mfma<<<1024, 256, 0, stream>>>(x, cbuf, (float*)d_out);
}

// Round 2
// 232.229 us; speedup vs baseline: 2.9901x; 2.9901x over previous
//
#include <hip/hip_runtime.h>
#include <hip/hip_bf16.h>

typedef __bf16        bf16x8 __attribute__((ext_vector_type(8)));
typedef float         f32x16 __attribute__((ext_vector_type(16)));
typedef unsigned int  u32x4  __attribute__((ext_vector_type(4)));
typedef unsigned int   u32;
typedef unsigned short u16;

__device__ __forceinline__ u16 f32_to_bf16(float f) {
    u32 u = __builtin_bit_cast(u32, f);
    u = (u + 0x7FFFu + ((u >> 16) & 1u)) >> 16;
    return (u16)u;
}
__device__ __forceinline__ u32 pack2bf(float a, float b) {
    return (u32)f32_to_bf16(a) | ((u32)f32_to_bf16(b) << 16);
}

// ---------------- kernel 1: build conv weights, bf16, layout [tap][oc][ic]
__global__ void build_c(const float* __restrict__ wxx,
                        const float* __restrict__ wid,
                        const float* __restrict__ XX,
                        const float* __restrict__ ident,
                        const int*   __restrict__ indsxx,
                        const int*   __restrict__ indsid,
                        u16*         __restrict__ cb)
{
    int idx = blockIdx.x * 256 + threadIdx.x;          // 25*128*128 = 409600
    if (idx >= 25 * 128 * 128) return;
    int b = idx & 127;            // ic2
    int a = (idx >> 7) & 127;     // oc2
    int t = idx >> 14;            // kh*5+kw
    int w2 = (a >> 1) * 64 + (b >> 1);
    float v = wxx[w2 * 5 + indsxx[t]] * XX[(a * 128 + b) * 25 + t]
            + ident[a * 128 + b]      * wid[w2 * 6 + indsid[t]];
    cb[idx] = f32_to_bf16(v);
}

// ---------------- kernel 2: implicit-GEMM conv, 32x32x16 bf16 MFMA
// 512 thr = 8 waves (2m x 4n). Block tile: 128 oc x (4 rows x 128 w).
// LDS: double-buffered x-stage [8 rows][132 wp][32 ic] bf16, XOR-swizzled 16B chunks.
__global__ void __launch_bounds__(512, 2)
conv_mfma(const float* __restrict__ x,
          const u16*   __restrict__ cb,
          float*       __restrict__ out)
{
    __shared__ u32x4 lds4[2 * 4224];                    // 2 x 8*132*4 chunks = 135168 B

    const int tid    = threadIdx.x;
    const int lane   = tid & 63;
    const int wv     = tid >> 6;
    const int wave_m = wv & 1;                           // oc half
    const int wave_n = wv >> 1;                          // output row 0..3
    const int l31    = lane & 31;
    const int h2     = lane >> 5;                        // K-chunk half

    // bijective XCD swizzle: 512 blocks, 64 per XCD (2 batches x 32 row-quads)
    const int bid  = blockIdx.x;
    const int sbid = (bid & 7) * 64 + (bid >> 3);
    const int bb   = sbid >> 5;                          // batch
    const int h0   = (sbid & 31) << 2;                   // output row base

    // staging mapping: thread -> (w column, ic-quad)
    const int wc     = tid & 127;                        // w 0..127
    const int icq    = tid >> 7;                         // 0..3
    const int wp_st  = wc + 2;
    const int st_idx = (wp_st << 2) + (icq ^ ((wp_st >> 1) & 3));  // + r*528

    // zero halo columns wp in {0,1,130,131}, both buffers, once
    if (tid < 256) {
        const int wtab[4] = {0, 1, 130, 131};
        int b  = tid >> 7;
        int t  = tid & 127;
        int r  = t >> 4, wq = (t >> 2) & 3, q = t & 3;
        u32x4 z = {0, 0, 0, 0};
        lds4[b * 4224 + r * 528 + (wtab[wq] << 2) + q] = z;
    }

    f32x16 acc[2][4];
    #pragma unroll
    for (int i = 0; i < 2; ++i)
        #pragma unroll
        for (int j = 0; j < 4; ++j)
            #pragma unroll
            for (int k = 0; k < 16; ++k) acc[i][j][k] = 0.f;

    float pf[8][8];                                      // prefetch regs [row][ic]
    const float* xb = x + (bb * 128 + icq * 8) * 16384 + wc;

    auto ISSUE = [&](int ich) {
        const float* bx = xb + ich * 32 * 16384;
        #pragma unroll
        for (int r = 0; r < 8; ++r) {
            int hp = h0 - 2 + r;
            if ((unsigned)hp < 128u) {
                const float* px = bx + hp * 128;
                #pragma unroll
                for (int k = 0; k < 8; ++k) pf[r][k] = px[k * 16384];
            } else {
                #pragma unroll
                for (int k = 0; k < 8; ++k) pf[r][k] = 0.f;
            }
        }
    };

    auto WRITE = [&](u32x4* buf) {
        #pragma unroll
        for (int r = 0; r < 8; ++r) {
            u32x4 v;
            v[0] = pack2bf(pf[r][0], pf[r][1]);
            v[1] = pack2bf(pf[r][2], pf[r][3]);
            v[2] = pack2bf(pf[r][4], pf[r][5]);
            v[3] = pack2bf(pf[r][6], pf[r][7]);
            buf[r * 528 + st_idx] = v;
        }
    };

    auto COMPUTE = [&](const u32x4* buf, int ich) {
        const u16* cbt = cb + (wave_m * 64 + l31) * 128 + ich * 32 + h2 * 8;
        #pragma unroll
        for (int kh = 0; kh < 5; ++kh) {
            const int rbase = (wave_n + kh) * 528;
            #pragma unroll
            for (int kw = 0; kw < 5; ++kw) {
                const u16* cp = cbt + (kh * 5 + kw) * 16384;
                const bf16x8 a0k0 = *reinterpret_cast<const bf16x8*>(cp);
                const bf16x8 a0k1 = *reinterpret_cast<const bf16x8*>(cp + 16);
                const bf16x8 a1k0 = *reinterpret_cast<const bf16x8*>(cp + 4096);
                const bf16x8 a1k1 = *reinterpret_cast<const bf16x8*>(cp + 4096 + 16);
                const int wsum = kw + l31;
                const int vsw  = (wsum >> 1) & 3;
                const int cb0  = rbase + (wsum << 2);
                const int i0   = cb0 + (h2 ^ vsw);            // kk=0 chunk
                const int i1   = cb0 + ((2 + h2) ^ vsw);      // kk=1 chunk
                #pragma unroll
                for (int nf = 0; nf < 4; ++nf) {
                    const bf16x8 b0 = __builtin_bit_cast(bf16x8, buf[i0 + nf * 128]);
                    const bf16x8 b1 = __builtin_bit_cast(bf16x8, buf[i1 + nf * 128]);
                    acc[0][nf] = __builtin_amdgcn_mfma_f32_32x32x16_bf16(a0k0, b0, acc[0][nf], 0, 0, 0);
                    acc[0][nf] = __builtin_amdgcn_mfma_f32_32x32x16_bf16(a0k1, b1, acc[0][nf], 0, 0, 0);
                    acc[1][nf] = __builtin_amdgcn_mfma_f32_32x32x16_bf16(a1k0, b0, acc[1][nf], 0, 0, 0);
                    acc[1][nf] = __builtin_amdgcn_mfma_f32_32x32x16_bf16(a1k1, b1, acc[1][nf], 0, 0, 0);
                }
            }
        }
    };

    // prologue: stage ich=0
    ISSUE(0);
    WRITE(lds4);
    __syncthreads();

    #pragma unroll 1
    for (int ich = 0; ich < 4; ++ich) {
        if (ich < 3) ISSUE(ich + 1);                     // loads in flight during compute
        COMPUTE(lds4 + (ich & 1) * 4224, ich);
        if (ich < 3) WRITE(lds4 + ((ich + 1) & 1) * 4224);
        __syncthreads();
    }

    // epilogue: D frag (32x32): col=lane&31 -> w, row=(reg&3)+8*(reg>>2)+4*h2 -> oc
    const int h = h0 + wave_n;
    float* ob = out + ((size_t)(bb * 128 + wave_m * 64) * 128 + h) * 128 + l31;
    #pragma unroll
    for (int mf = 0; mf < 2; ++mf)
        #pragma unroll
        for (int reg = 0; reg < 16; ++reg) {
            const int oc = mf * 32 + (reg & 3) + ((reg >> 2) << 3) + (h2 << 2);
            float* op = ob + (size_t)oc * 16384;
            #pragma unroll
            for (int nf = 0; nf < 4; ++nf)
                op[nf * 32] = acc[mf][nf][reg];
        }
}

extern "C" void kernel_launch(void* const* d_in, const int* in_sizes, int n_in,
                              void* d_out, int out_size, void* d_ws, size_t ws_size,
                              hipStream_t stream)
{
    const float* x    = (const float*)d_in[0];
    const float* wxx  = (const float*)d_in[1];
    const float* wi   = (const float*)d_in[2];
    const float* XX   = (const float*)d_in[3];
    const float* iden = (const float*)d_in[4];
    const int*   ixx  = (const int*)d_in[5];
    const int*   iid  = (const int*)d_in[6];

    u16* cbuf = (u16*)d_ws;                              // 819200 B scratch

    build_c<<<1600, 256, 0, stream>>>(wxx, wi, XX, iden, ixx, iid, cbuf);
    conv_mfma<<<512, 512, 0, stream>>>(x, cbuf, (float*)d_out);
}